// Round 5
// baseline (1727.416 us; speedup 1.0000x reference)
//
#include <hip/hip_runtime.h>
#include <math.h>

#define N_NODES 100000
#define N_FEAT  512
#define HIDDEN  256
#define N_CLS   40
#define N_EDGES 1600000
#define K_HOPS  10
#define SCAN_BLOCKS 98       // 98*1024 = 100352 >= N_NODES+1
#define PLANE   (N_NODES * 8)  // one class-plane: [node][8 bf16] (5 used), 1.6 MB

typedef __attribute__((ext_vector_type(8))) short short8;   // 8 bf16
typedef __attribute__((ext_vector_type(4))) float f4_t;

__device__ __forceinline__ short f2bf(float f) {
    union { float f; unsigned u; } x; x.f = f;
    unsigned r = x.u + 0x7fffu + ((x.u >> 16) & 1u);  // RNE
    return (short)(r >> 16);
}

__device__ __forceinline__ float bf2f(short b) {
    union { unsigned u; float f; } x;
    x.u = ((unsigned)(unsigned short)b) << 16;
    return x.f;
}

// ---------------------------------------------------------------- prep kernels

__global__ __launch_bounds__(256) void init_deg_kernel(int* __restrict__ deg) {
    int v = blockIdx.x * 256 + threadIdx.x;
    if (v < N_NODES) deg[v] = 1;  // self-loop
}

__global__ __launch_bounds__(256) void count_dst_kernel(const int* __restrict__ dst,
                                                        int* __restrict__ deg) {
    int e = blockIdx.x * 256 + threadIdx.x;
    if (e < N_EDGES) atomicAdd(&deg[dst[e]], 1);
}

__global__ __launch_bounds__(256) void rsqrt_deg_kernel(const int* __restrict__ deg,
                                                        float* __restrict__ d) {
    int v = blockIdx.x * 256 + threadIdx.x;
    if (v < N_NODES) d[v] = rsqrtf((float)deg[v]);
}

// ---- 3-phase device-wide exclusive scan of deg -> rowptr/cursor (coalesced)

__global__ __launch_bounds__(1024) void scan_partial_kernel(const int* __restrict__ deg,
                                                            int* __restrict__ blocksum) {
    __shared__ int s[1024];
    int t = threadIdx.x;
    int idx = blockIdx.x * 1024 + t;
    s[t] = (idx < N_NODES) ? deg[idx] : 0;
    __syncthreads();
#pragma unroll
    for (int off = 512; off > 0; off >>= 1) {
        if (t < off) s[t] += s[t + off];
        __syncthreads();
    }
    if (t == 0) blocksum[blockIdx.x] = s[0];
}

__global__ __launch_bounds__(64) void scan_blocks_kernel(const int* __restrict__ blocksum,
                                                         int* __restrict__ blockoff) {
    if (threadIdx.x == 0) {
        int run = 0;
        for (int b = 0; b < SCAN_BLOCKS; ++b) { blockoff[b] = run; run += blocksum[b]; }
    }
}

__global__ __launch_bounds__(1024) void scan_write_kernel(const int* __restrict__ deg,
                                                          const int* __restrict__ blockoff,
                                                          int* __restrict__ rowptr,
                                                          int* __restrict__ cursor) {
    __shared__ int s[1024];
    int t = threadIdx.x;
    int idx = blockIdx.x * 1024 + t;
    int v = (idx < N_NODES) ? deg[idx] : 0;
    s[t] = v;
    __syncthreads();
#pragma unroll
    for (int off = 1; off < 1024; off <<= 1) {
        int add = (t >= off) ? s[t - off] : 0;
        __syncthreads();
        s[t] += add;
        __syncthreads();
    }
    int pre = s[t] - v + blockoff[blockIdx.x];  // exclusive prefix
    if (idx <= N_NODES) rowptr[idx] = pre;
    if (idx < N_NODES) cursor[idx] = pre;
}

__global__ __launch_bounds__(256) void scatter_edges_kernel(const int* __restrict__ src,
                                                            const int* __restrict__ dst,
                                                            const float* __restrict__ d,
                                                            int* __restrict__ cursor,
                                                            int2* __restrict__ epair) {
    int e = blockIdx.x * 256 + threadIdx.x;
    if (e >= N_EDGES) return;
    int u = src[e], v = dst[e];
    int pos = atomicAdd(&cursor[v], 1);
    int2 p;
    p.x = u;
    p.y = __float_as_int(d[u] * d[v]);
    epair[pos] = p;
}

__global__ __launch_bounds__(256) void scatter_self_kernel(const float* __restrict__ d,
                                                           int* __restrict__ cursor,
                                                           int2* __restrict__ epair) {
    int v = blockIdx.x * 256 + threadIdx.x;
    if (v >= N_NODES) return;
    int pos = atomicAdd(&cursor[v], 1);
    float dv = d[v];
    int2 p;
    p.x = v;
    p.y = __float_as_int(dv * dv);
    epair[pos] = p;
}

// W1 [512][256] f32 -> W1T [256][512] bf16 (col-major: per-col k contiguous)
__global__ __launch_bounds__(256) void cvt_w1_kernel(const float* __restrict__ W1,
                                                     short* __restrict__ W1T) {
    int lin = blockIdx.x * 256 + threadIdx.x;  // 131072
    int k = lin >> 8, n = lin & 255;
    W1T[n * 512 + k] = f2bf(W1[lin]);
}

// W2 [256][40] f32 -> W2T [64][256] bf16, rows >=40 zero
__global__ __launch_bounds__(256) void cvt_w2_kernel(const float* __restrict__ W2,
                                                     short* __restrict__ W2T) {
    int lin = blockIdx.x * 256 + threadIdx.x;  // 16384
    int n = lin >> 8, k = lin & 255;
    W2T[lin] = (n < N_CLS) ? f2bf(W2[k * N_CLS + n]) : (short)0;
}

// ---------------------------------------------------------------- fused MLP (MFMA)
// Block = 256 thr (4 waves), 64 rows. Phase A: h1 = relu(feat@W1+b1) -> sH (bf16).
// Phase B: out = sH @ W2 + b2 -> h (bf16 class-planes), TH (fp32).
__global__ __launch_bounds__(256) void mlp_kernel(const float* __restrict__ feat,
                                                  const short* __restrict__ W1T,
                                                  const float* __restrict__ b1,
                                                  const short* __restrict__ W2T,
                                                  const float* __restrict__ b2,
                                                  const float* __restrict__ temp,
                                                  short* __restrict__ h,
                                                  float* __restrict__ TH) {
    __shared__ union {
        struct { short A[64][72]; short B[256][72]; } a;  // 9216 + 36864 B
        short W2s[48][264];                               // 25344 B
    } uS;
    __shared__ short sH[64][264];                         // 33792 B

    const int tid = threadIdx.x;
    const int rbase = blockIdx.x * 64;
    const int lane = tid & 63;
    const int wv = tid >> 6;       // wave 0..3
    const int quad = lane >> 4;    // 0..3
    const int l15 = lane & 15;

    f4_t acc[4][4];
#pragma unroll
    for (int m = 0; m < 4; ++m)
#pragma unroll
        for (int n = 0; n < 4; ++n) acc[m][n] = (f4_t)0.f;

    const int arow = tid >> 2;
    const int akq = tid & 3;
    for (int kt = 0; kt < 8; ++kt) {
        __syncthreads();
        {
            int grow = rbase + arow;
            f4_t f0 = (f4_t)0.f, f1 = (f4_t)0.f, f2 = (f4_t)0.f, f3 = (f4_t)0.f;
            if (grow < N_NODES) {
                const f4_t* p = (const f4_t*)(feat + grow * N_FEAT + kt * 64 + akq * 16);
                f0 = p[0]; f1 = p[1]; f2 = p[2]; f3 = p[3];
            }
            short8 lo, hi;
            lo[0]=f2bf(f0[0]); lo[1]=f2bf(f0[1]); lo[2]=f2bf(f0[2]); lo[3]=f2bf(f0[3]);
            lo[4]=f2bf(f1[0]); lo[5]=f2bf(f1[1]); lo[6]=f2bf(f1[2]); lo[7]=f2bf(f1[3]);
            hi[0]=f2bf(f2[0]); hi[1]=f2bf(f2[1]); hi[2]=f2bf(f2[2]); hi[3]=f2bf(f2[3]);
            hi[4]=f2bf(f3[0]); hi[5]=f2bf(f3[1]); hi[6]=f2bf(f3[2]); hi[7]=f2bf(f3[3]);
            short8* dstp = (short8*)&uS.a.A[arow][akq * 16];
            dstp[0] = lo; dstp[1] = hi;
        }
#pragma unroll
        for (int p = 0; p < 8; ++p) {
            int lin = p * 256 + tid;
            int col = lin >> 3, kc = lin & 7;
            *(short8*)&uS.a.B[col][kc * 8] =
                *(const short8*)(W1T + col * 512 + kt * 64 + kc * 8);
        }
        __syncthreads();
#pragma unroll
        for (int kk = 0; kk < 64; kk += 32) {
            short8 af[4], bf[4];
#pragma unroll
            for (int m = 0; m < 4; ++m)
                af[m] = *(const short8*)&uS.a.A[m * 16 + l15][kk + quad * 8];
#pragma unroll
            for (int n = 0; n < 4; ++n)
                bf[n] = *(const short8*)&uS.a.B[wv * 64 + n * 16 + l15][kk + quad * 8];
#pragma unroll
            for (int m = 0; m < 4; ++m)
#pragma unroll
                for (int n = 0; n < 4; ++n)
                    acc[m][n] = __builtin_amdgcn_mfma_f32_16x16x32_bf16(af[m], bf[n],
                                                                        acc[m][n], 0, 0, 0);
        }
    }
    __syncthreads();

#pragma unroll
    for (int n = 0; n < 4; ++n) {
        int col = wv * 64 + n * 16 + l15;
        float bb = b1[col];
#pragma unroll
        for (int m = 0; m < 4; ++m)
#pragma unroll
            for (int r = 0; r < 4; ++r) {
                float v = acc[m][n][r] + bb;
                sH[m * 16 + quad * 4 + r][col] = f2bf(v > 0.f ? v : 0.f);
            }
    }
#pragma unroll
    for (int p = 0; p < 6; ++p) {
        int lin = p * 256 + tid;
        int n = lin >> 5, kc = lin & 31;
        *(short8*)&uS.W2s[n][kc * 8] = *(const short8*)(W2T + n * 256 + kc * 8);
    }
    __syncthreads();

    f4_t accB[3];
#pragma unroll
    for (int n = 0; n < 3; ++n) accB[n] = (f4_t)0.f;
#pragma unroll
    for (int kk = 0; kk < 256; kk += 32) {
        short8 a = *(const short8*)&sH[wv * 16 + l15][kk + quad * 8];
#pragma unroll
        for (int n = 0; n < 3; ++n) {
            short8 b = *(const short8*)&uS.W2s[n * 16 + l15][kk + quad * 8];
            accB[n] = __builtin_amdgcn_mfma_f32_16x16x32_bf16(a, b, accB[n], 0, 0, 0);
        }
    }
    float t0 = temp[0];
#pragma unroll
    for (int n = 0; n < 3; ++n) {
        int col = n * 16 + l15;
        if (col < N_CLS) {
            float bb = b2[col];
            int plane = col / 5;
            int ci = col - plane * 5;
#pragma unroll
            for (int r = 0; r < 4; ++r) {
                int grow = rbase + wv * 16 + quad * 4 + r;
                if (grow < N_NODES) {
                    float v = accB[n][r] + bb;
                    h[plane * PLANE + grow * 8 + ci] = f2bf(v);
                    TH[grow * N_CLS + col] = t0 * v;
                }
            }
        }
    }
}

// ---------------------------------------------------------------- propagation
// XCD-sliced pull SpMM: block b handles class-group g = b%8 (5 classes).
// Group g's gather target is one 1.6 MB plane -> L2-resident per XCD.
__global__ __launch_bounds__(256) void prop_kernel(const short* __restrict__ h,
                                                   short* __restrict__ hn,
                                                   const int* __restrict__ rowptr,
                                                   const int2* __restrict__ epair,
                                                   float* __restrict__ TH,
                                                   const float* __restrict__ temp,
                                                   int kidx) {
    const int g = blockIdx.x & 7;
    const int v = (blockIdx.x >> 3) * 256 + threadIdx.x;
    if (v >= N_NODES) return;
    const short* hp = h + g * PLANE;
    int s = rowptr[v], e = rowptr[v + 1];
    float a0 = 0.f, a1 = 0.f, a2 = 0.f, a3 = 0.f, a4 = 0.f;
    int j = s;
    for (; j + 4 <= e; j += 4) {
        int2 p0 = epair[j], p1 = epair[j + 1], p2 = epair[j + 2], p3 = epair[j + 3];
        short8 x0 = *(const short8*)(hp + p0.x * 8);
        short8 x1 = *(const short8*)(hp + p1.x * 8);
        short8 x2 = *(const short8*)(hp + p2.x * 8);
        short8 x3 = *(const short8*)(hp + p3.x * 8);
        float w0 = __int_as_float(p0.y), w1 = __int_as_float(p1.y);
        float w2 = __int_as_float(p2.y), w3 = __int_as_float(p3.y);
        a0 += w0 * bf2f(x0[0]) + w1 * bf2f(x1[0]) + w2 * bf2f(x2[0]) + w3 * bf2f(x3[0]);
        a1 += w0 * bf2f(x0[1]) + w1 * bf2f(x1[1]) + w2 * bf2f(x2[1]) + w3 * bf2f(x3[1]);
        a2 += w0 * bf2f(x0[2]) + w1 * bf2f(x1[2]) + w2 * bf2f(x2[2]) + w3 * bf2f(x3[2]);
        a3 += w0 * bf2f(x0[3]) + w1 * bf2f(x1[3]) + w2 * bf2f(x2[3]) + w3 * bf2f(x3[3]);
        a4 += w0 * bf2f(x0[4]) + w1 * bf2f(x1[4]) + w2 * bf2f(x2[4]) + w3 * bf2f(x3[4]);
    }
    for (; j < e; ++j) {
        int2 p = epair[j];
        short8 x = *(const short8*)(hp + p.x * 8);
        float w = __int_as_float(p.y);
        a0 += w * bf2f(x[0]);
        a1 += w * bf2f(x[1]);
        a2 += w * bf2f(x[2]);
        a3 += w * bf2f(x[3]);
        a4 += w * bf2f(x[4]);
    }
    float tk = temp[kidx];
    short8 ob;
    ob[0] = f2bf(a0); ob[1] = f2bf(a1); ob[2] = f2bf(a2); ob[3] = f2bf(a3); ob[4] = f2bf(a4);
    ob[5] = 0; ob[6] = 0; ob[7] = 0;
    *(short8*)(hn + g * PLANE + v * 8) = ob;
    float* pt = TH + v * N_CLS + g * 5;
    pt[0] += tk * a0;
    pt[1] += tk * a1;
    pt[2] += tk * a2;
    pt[3] += tk * a3;
    pt[4] += tk * a4;
}

// ---------------------------------------------------------------- log_softmax
__global__ __launch_bounds__(256) void lsm_kernel(float* __restrict__ out) {
    int wid = (blockIdx.x * 256 + threadIdx.x) >> 6;
    int lane = threadIdx.x & 63;
    if (wid >= N_NODES) return;
    float x = (lane < N_CLS) ? out[wid * N_CLS + lane] : -INFINITY;
    float m = x;
#pragma unroll
    for (int o = 32; o > 0; o >>= 1) m = fmaxf(m, __shfl_xor(m, o, 64));
    float e = (lane < N_CLS) ? expf(x - m) : 0.f;
    float s = e;
#pragma unroll
    for (int o = 32; o > 0; o >>= 1) s += __shfl_xor(s, o, 64);
    float r = x - m - logf(s);
    if (lane < N_CLS) out[wid * N_CLS + lane] = r;
}

// ---------------------------------------------------------------- launch

extern "C" void kernel_launch(void* const* d_in, const int* in_sizes, int n_in,
                              void* d_out, int out_size, void* d_ws, size_t ws_size,
                              hipStream_t stream) {
    const float* feat = (const float*)d_in[0];
    const float* W1   = (const float*)d_in[1];
    const float* b1   = (const float*)d_in[2];
    const float* W2   = (const float*)d_in[3];
    const float* b2   = (const float*)d_in[4];
    const float* temp = (const float*)d_in[5];
    const int*   src  = (const int*)d_in[6];
    const int*   dst  = (const int*)d_in[7];
    float* out = (float*)d_out;

    // workspace layout (bytes). deg region reused for W1T/W2T after scan.
    char* ws = (char*)d_ws;
    int*   deg    = (int*)(ws + 0);          //  400000 B (dead after scan_write)
    short* W1T    = (short*)(ws + 0);        //  262144 B (overlaps deg)
    short* W2T    = (short*)(ws + 262144);   //   32768 B
    float* dnorm  = (float*)(ws + 400000);   //  400000 B
    int*   rowptr = (int*)(ws + 800000);     //  400004 B
    int*   cursor = (int*)(ws + 1200016);    //  400000 B
    int2*  epair  = (int2*)(ws + 1600032);   // 13600000 B
    short* h0     = (short*)(ws + 15200032); // 12800000 B (8 bf16 class-planes)
    short* h1     = (short*)(ws + 28000032); // 12800000 B
    int*   blocksum = (int*)(ws + 40800032); //   392 B
    int*   blockoff = (int*)(ws + 40800432); //   392 B  -> end 40800824

    init_deg_kernel<<<(N_NODES + 255) / 256, 256, 0, stream>>>(deg);
    count_dst_kernel<<<(N_EDGES + 255) / 256, 256, 0, stream>>>(dst, deg);
    rsqrt_deg_kernel<<<(N_NODES + 255) / 256, 256, 0, stream>>>(deg, dnorm);
    scan_partial_kernel<<<SCAN_BLOCKS, 1024, 0, stream>>>(deg, blocksum);
    scan_blocks_kernel<<<1, 64, 0, stream>>>(blocksum, blockoff);
    scan_write_kernel<<<SCAN_BLOCKS, 1024, 0, stream>>>(deg, blockoff, rowptr, cursor);
    cvt_w1_kernel<<<512, 256, 0, stream>>>(W1, W1T);
    cvt_w2_kernel<<<64, 256, 0, stream>>>(W2, W2T);
    scatter_edges_kernel<<<(N_EDGES + 255) / 256, 256, 0, stream>>>(src, dst, dnorm, cursor,
                                                                    epair);
    scatter_self_kernel<<<(N_NODES + 255) / 256, 256, 0, stream>>>(dnorm, cursor, epair);

    mlp_kernel<<<(N_NODES + 63) / 64, 256, 0, stream>>>(feat, W1T, b1, W2T, b2, temp, h0, out);

    const int NB = (N_NODES + 255) / 256;  // node chunks per class-group
    short* hc = h0;
    short* hn = h1;
    for (int k = 0; k < K_HOPS; ++k) {
        prop_kernel<<<NB * 8, 256, 0, stream>>>(hc, hn, rowptr, epair, out, temp, k + 1);
        short* t = hc; hc = hn; hn = t;
    }

    lsm_kernel<<<(N_NODES / 4), 256, 0, stream>>>(out);
}